// Round 9
// baseline (845.992 us; speedup 1.0000x reference)
//
#include <hip/hip_runtime.h>
#include <hip/hip_bf16.h>
#include <stdint.h>
#include <stddef.h>

typedef __bf16 bf16_t;
typedef __attribute__((ext_vector_type(8))) __bf16 bf16x8;
typedef __attribute__((ext_vector_type(4))) __bf16 bf16x4;
typedef __attribute__((ext_vector_type(4))) float f32x4;

#define HDIM 1024
#define MSLOTS 16384
#define NROWS 8192  // B*S

__device__ __forceinline__ void load16_lds(const void* g, void* l) {
  __builtin_amdgcn_global_load_lds((const __attribute__((address_space(1))) void*)g,
                                   (__attribute__((address_space(3))) void*)l, 16, 0, 0);
}

// Single-block deterministic compaction (also zeroes cmask): posmap[pos] = slot for
// used slots (sorted), cmask[pos]=1, smalls[0]=count, smalls[1]=count padded to 512.
__global__ void compact_scan(const int* __restrict__ usage, int* __restrict__ posmap,
                             int* __restrict__ cmask, int* __restrict__ smalls) {
  __shared__ int wtot[16], wbase[16];
  const int t = threadIdx.x;          // 0..1023
  const int lane = t & 63, wid = t >> 6;
  for (int i = t; i < MSLOTS; i += 1024) cmask[i] = 0;
  __syncthreads();
  const int base = t * 16;
  unsigned mask = 0;
  int c = 0;
  #pragma unroll
  for (int i = 0; i < 16; ++i) {
    if (usage[base + i] > 0) { mask |= (1u << i); ++c; }
  }
  int inc = c;
  #pragma unroll
  for (int d = 1; d < 64; d <<= 1) {
    int n = __shfl_up(inc, d);
    if (lane >= d) inc += n;
  }
  if (lane == 63) wtot[wid] = inc;
  __syncthreads();
  if (t == 0) {
    int acc = 0;
    #pragma unroll
    for (int w = 0; w < 16; ++w) { wbase[w] = acc; acc += wtot[w]; }
    smalls[0] = acc;
    smalls[1] = ((acc + 511) >> 9) << 9;
  }
  __syncthreads();
  int pos = wbase[wid] + inc - c;
  #pragma unroll
  for (int i = 0; i < 16; ++i) {
    if ((mask >> i) & 1u) {
      posmap[pos] = base + i;
      cmask[pos] = 1;
      ++pos;
    }
  }
}

// fp32 -> bf16 convert, 8 elems/thread
__global__ void cvt_f32_bf16(const float* __restrict__ X, bf16_t* __restrict__ Y, int n8) {
  int i = blockIdx.x * blockDim.x + threadIdx.x;
  if (i >= n8) return;
  float4 a = ((const float4*)X)[2 * i];
  float4 b = ((const float4*)X)[2 * i + 1];
  bf16x8 o;
  o[0] = (bf16_t)a.x; o[1] = (bf16_t)a.y; o[2] = (bf16_t)a.z; o[3] = (bf16_t)a.w;
  o[4] = (bf16_t)b.x; o[5] = (bf16_t)b.y; o[6] = (bf16_t)b.z; o[7] = (bf16_t)b.w;
  ((bf16x8*)Y)[i] = o;
}

// L2-normalize rows of length 1024, fp32 in -> bf16 out (for q)
__global__ void normalize_rows(const float* __restrict__ X, bf16_t* __restrict__ Y) {
  __shared__ float part[4];
  const int t = threadIdx.x;
  const size_t row = blockIdx.x;
  float4 v = ((const float4*)(X + row * 1024))[t];
  float s = v.x * v.x + v.y * v.y + v.z * v.z + v.w * v.w;
  #pragma unroll
  for (int m = 32; m >= 1; m >>= 1) s += __shfl_xor(s, m);
  if ((t & 63) == 0) part[t >> 6] = s;
  __syncthreads();
  float tot = part[0] + part[1] + part[2] + part[3];
  float r = rsqrtf(tot + 1e-6f);
  bf16x4 o;
  o[0] = (bf16_t)(v.x * r); o[1] = (bf16_t)(v.y * r);
  o[2] = (bf16_t)(v.z * r); o[3] = (bf16_t)(v.w * r);
  *(bf16x4*)&Y[row * 1024 + t * 4] = o;
}

// cmkn[p] = normalize(mk[posmap[p]]) for p<cnt; zeros for cnt<=p<mpad. No atomics.
__global__ void normalize_gather(const float* __restrict__ mk, const int* __restrict__ posmap,
                                 const int* __restrict__ smalls, bf16_t* __restrict__ cmkn) {
  __shared__ float part[4];
  const int p = blockIdx.x;
  const int cnt = smalls[0], mpad = smalls[1];
  if (p >= mpad) return;
  const int t = threadIdx.x;
  if (p >= cnt) {
    bf16x4 z;
    z[0] = z[1] = z[2] = z[3] = (bf16_t)0.f;
    *(bf16x4*)&cmkn[(size_t)p * 1024 + t * 4] = z;
    return;
  }
  const int slot = posmap[p];
  float4 v = ((const float4*)(mk + (size_t)slot * 1024))[t];
  float s = v.x * v.x + v.y * v.y + v.z * v.z + v.w * v.w;
  #pragma unroll
  for (int m = 32; m >= 1; m >>= 1) s += __shfl_xor(s, m);
  if ((t & 63) == 0) part[t >> 6] = s;
  __syncthreads();
  float tot = part[0] + part[1] + part[2] + part[3];
  float r = rsqrtf(tot + 1e-6f);
  bf16x4 o;
  o[0] = (bf16_t)(v.x * r); o[1] = (bf16_t)(v.y * r);
  o[2] = (bf16_t)(v.z * r); o[3] = (bf16_t)(v.w * r);
  *(bf16x4*)&cmkn[(size_t)p * 1024 + t * 4] = o;
}

// cVt[h][pos] = pos<cnt ? mv[posmap[pos]][h] : 0, for pos < mpad
__global__ void transpose_gather(const float* __restrict__ mv, const int* __restrict__ posmap,
                                 const int* __restrict__ smalls, bf16_t* __restrict__ cVt) {
  __shared__ float tile[32][33];
  const int cnt = smalls[0], mpad = smalls[1];
  const int p0 = blockIdx.y * 32;
  if (p0 >= mpad) return;
  const int tx = threadIdx.x & 31, ty = threadIdx.x >> 5;  // 32 x 8
  const int h0 = blockIdx.x * 32;
  #pragma unroll
  for (int j = 0; j < 32; j += 8) {
    const int pos = p0 + ty + j;
    float val = 0.f;
    if (pos < cnt) val = mv[(size_t)posmap[pos] * 1024 + h0 + tx];
    tile[ty + j][tx] = val;
  }
  __syncthreads();
  #pragma unroll
  for (int j = 0; j < 32; j += 8)
    cVt[(size_t)(h0 + ty + j) * MSLOTS + p0 + tx] = (bf16_t)tile[tx][ty + j];
}

__global__ void zero_f32(float* __restrict__ p, int n4) {
  int i = blockIdx.x * blockDim.x + threadIdx.x;
  if (i < n4) ((float4*)p)[i] = (float4){0.f, 0.f, 0.f, 0.f};
}

// out = retrf * (1/den[row]) -> bf16 (atomic split-K mode)
__global__ void scale_cvt(const float* __restrict__ retrf, const float* __restrict__ den,
                          bf16_t* __restrict__ out, int n4) {
  int i = blockIdx.x * blockDim.x + threadIdx.x;
  if (i >= n4) return;
  float4 s = ((const float4*)retrf)[i];
  const int row = (i * 4) >> 10;  // HDIM=1024
  const float r = 1.0f / den[row];
  bf16x4 o;
  o[0] = (bf16_t)(s.x * r); o[1] = (bf16_t)(s.y * r);
  o[2] = (bf16_t)(s.z * r); o[3] = (bf16_t)(s.w * r);
  ((bf16x4*)out)[i] = o;
}

// sum ks bf16 partial slabs (fp32 accumulate), scale by 1/den[row], store bf16.
__global__ void reduce_scale_b(const bf16_t* __restrict__ part, size_t partStride, int ks,
                               const float* __restrict__ den, bf16_t* __restrict__ out,
                               int n8) {
  int i = blockIdx.x * blockDim.x + threadIdx.x;
  if (i >= n8) return;
  float acc[8];
  #pragma unroll
  for (int e = 0; e < 8; ++e) acc[e] = 0.f;
  for (int k = 0; k < ks; ++k) {
    bf16x8 v = ((const bf16x8*)(part + (size_t)k * partStride))[i];
    #pragma unroll
    for (int e = 0; e < 8; ++e) acc[e] += (float)v[e];
  }
  const int row = (i * 8) >> 10;  // HDIM=1024
  const float r = 1.0f / den[row];
  bf16x8 o;
  #pragma unroll
  for (int e = 0; e < 8; ++e) o[e] = (bf16_t)(acc[e] * r);
  ((bf16x8*)out)[i] = o;
}

// m97-style 128x128 bf16 GEMM, C = A * Bt^T. A:[rows,ldk], Bt:[N,ldk] row-major.
// All EPIs: XCD swizzle, y-inner order (ylow -> XCD, then yhigh, then x, then z).
// EPI 0: outf = acc + bias[col]                                   (fp32 out)
// EPI 1: outb = cmask[col] ? exp(10*acc) : 0 (bf16) + row sums -> den
//        (block-local LDS combine, then 128 coalesced global atomics/block)
// EPI 3: split-K over K=mpad: atomicAdd(outf, acc)                (fp32 accumulate)
// EPI 4: split-K over K=mpad: outb[z-slab] = acc                  (bf16 partial store)
template <int EPI>
__global__ void gemm_bt(const bf16_t* __restrict__ A, const bf16_t* __restrict__ Bt,
                        int ldk, int kLenIn, int ldc,
                        const float* __restrict__ bias,
                        const int* __restrict__ cmask,
                        float* __restrict__ den,
                        float* __restrict__ outf, bf16_t* __restrict__ outb,
                        const int* __restrict__ smalls, int ks, size_t partStride) {
  __shared__ bf16_t lA[128 * 32];
  __shared__ bf16_t lB[128 * 32];
  __shared__ float sden[128];
  const int t = threadIdx.x;
  const int lane = t & 63;
  const int wave = t >> 6;
  const int wm = (wave >> 1) << 6;  // wave tile origin (2x2 waves of 64x64)
  const int wn = (wave & 1) << 6;
  const int lr = lane & 15;
  const int lq = lane >> 4;

  int bx = blockIdx.x, by = blockIdx.y, bz = blockIdx.z;
  {
    const unsigned nx = gridDim.x, ny = gridDim.y;
    if ((ny & 7u) == 0u) {
      unsigned lin = blockIdx.x + nx * (blockIdx.y + ny * blockIdx.z);
      unsigned ylow = lin & 7u;   // XCD id under round-robin dispatch
      lin >>= 3;
      const unsigned nyh = ny >> 3;
      unsigned yhigh = lin % nyh; // y-inner: B-tile reused by stream-adjacent blocks
      lin /= nyh;
      bx = lin % nx;
      bz = lin / nx;
      by = ylow + 8u * yhigh;
    }
  }

  int kLen = kLenIn;
  int kstart = 0;
  if (EPI == 1) {
    if (bx * 128 >= smalls[1]) return;  // compacted N bound (block-uniform)
  }
  if (EPI == 3 || EPI == 4) {
    kLen = smalls[1] / ks;  // mpad % 512 == 0 -> kLen % 32 == 0 for ks in {4,8,16}
    kstart = bz * kLen;
  }

  // Tile staging: 128 rows x 32 K-cols = 8192 B per array; 256 thr x 16 B = half,
  // so each thread issues TWO global_load_lds per array (rows 0-63 and 64-127).
  const int r0 = t >> 2;         // 0..63
  const int c0 = (t & 3) * 8;    // 0,8,16,24
  const bf16_t* pA0 = A + (size_t)(by * 128 + r0) * ldk + kstart + c0;
  const bf16_t* pA1 = pA0 + (size_t)64 * ldk;
  const bf16_t* pB0 = Bt + (size_t)(bx * 128 + r0) * ldk + kstart + c0;
  const bf16_t* pB1 = pB0 + (size_t)64 * ldk;

  f32x4 acc[4][4];
  #pragma unroll
  for (int i = 0; i < 4; ++i)
    #pragma unroll
    for (int j = 0; j < 4; ++j) acc[i][j] = (f32x4){0.f, 0.f, 0.f, 0.f};

  for (int k0 = 0; k0 < kLen; k0 += 32) {
    __syncthreads();
    load16_lds(pA0, &lA[t * 8]);
    load16_lds(pA1, &lA[2048 + t * 8]);
    load16_lds(pB0, &lB[t * 8]);
    load16_lds(pB1, &lB[2048 + t * 8]);
    pA0 += 32; pA1 += 32; pB0 += 32; pB1 += 32;
    __syncthreads();
    bf16x8 af[4], bfr[4];
    #pragma unroll
    for (int i = 0; i < 4; ++i)
      af[i] = *(const bf16x8*)&lA[(wm + i * 16 + lr) * 32 + lq * 8];
    #pragma unroll
    for (int j = 0; j < 4; ++j)
      bfr[j] = *(const bf16x8*)&lB[(wn + j * 16 + lr) * 32 + lq * 8];
    #pragma unroll
    for (int i = 0; i < 4; ++i)
      #pragma unroll
      for (int j = 0; j < 4; ++j)
        acc[i][j] = __builtin_amdgcn_mfma_f32_16x16x32_bf16(af[i], bfr[j], acc[i][j], 0, 0, 0);
  }

  // C/D layout (m89-verified): col = lane&15, row = (lane>>4)*4 + r
  const int colBase = bx * 128 + wn + lr;
  const int rowBase = by * 128 + wm + lq * 4;

  if (EPI == 4) outb += (size_t)bz * partStride;

  float rs[4][4];  // per-(i,r) row-sum accumulators (EPI==1)
  if (EPI == 1) {
    #pragma unroll
    for (int i = 0; i < 4; ++i)
      #pragma unroll
      for (int r = 0; r < 4; ++r) rs[i][r] = 0.f;
  }

  #pragma unroll
  for (int j = 0; j < 4; ++j) {
    const int col = colBase + j * 16;
    float bval = 0.f;
    bool ok = true;
    if (EPI == 0) bval = bias[col];
    if (EPI == 1) ok = cmask[col] > 0;
    #pragma unroll
    for (int i = 0; i < 4; ++i) {
      const int row = rowBase + i * 16;
      #pragma unroll
      for (int r = 0; r < 4; ++r) {
        const size_t idx = (size_t)(row + r) * ldc + col;
        float v = acc[i][j][r];
        if (EPI == 0) outf[idx] = v + bval;
        if (EPI == 1) {
          float e = ok ? exp2f(v * 14.426950408889634f) : 0.f;
          rs[i][r] += e;
          outb[idx] = (bf16_t)e;
        }
        if (EPI == 3) atomicAdd(&outf[idx], v);
        if (EPI == 4) outb[idx] = (bf16_t)v;
      }
    }
  }

  if (EPI == 1) {
    // block-local row sums in LDS, then 128 coalesced global atomics per block
    if (t < 128) sden[t] = 0.f;
    __syncthreads();
    #pragma unroll
    for (int i = 0; i < 4; ++i)
      #pragma unroll
      for (int r = 0; r < 4; ++r) {
        float s = rs[i][r];
        s += __shfl_xor(s, 1);
        s += __shfl_xor(s, 2);
        s += __shfl_xor(s, 4);
        s += __shfl_xor(s, 8);
        if (lr == 0) atomicAdd(&sden[wm + i * 16 + lq * 4 + r], s);
      }
    __syncthreads();
    if (t < 128) atomicAdd(&den[by * 128 + t], sden[t]);
  }
}

extern "C" void kernel_launch(void* const* d_in, const int* in_sizes, int n_in,
                              void* d_out, int out_size, void* d_ws, size_t ws_size,
                              hipStream_t stream) {
  const float* hs = (const float*)d_in[0];
  const float* Wk = (const float*)d_in[1];
  const float* bk = (const float*)d_in[2];
  // d_in[3]=Wv, d_in[4]=bv are unused by the reference
  const float* Wo = (const float*)d_in[5];
  const float* bo = (const float*)d_in[6];
  const float* mk = (const float*)d_in[7];
  const float* mv = (const float*)d_in[8];
  const int* usage = (const int*)d_in[9];
  float* out = (float*)d_out;

  char* ws = (char*)d_ws;
  size_t off = 0;
  auto alloc = [&](size_t b) -> void* {
    void* p = ws + off;
    off += (b + 255) & ~(size_t)255;
    return p;
  };
  // Persistent buffers (live across the chunk loop)
  bf16_t* cmkn = (bf16_t*)alloc((size_t)MSLOTS * HDIM * 2);
  bf16_t* cVt = (bf16_t*)alloc((size_t)HDIM * MSLOTS * 2);
  bf16_t* qnb = (bf16_t*)alloc((size_t)NROWS * HDIM * 2);
  bf16_t* retrb = (bf16_t*)alloc((size_t)NROWS * HDIM * 2);
  float* den = (float*)alloc((size_t)NROWS * 4);
  int* posmap = (int*)alloc((size_t)MSLOTS * 4);
  int* cmask = (int*)alloc((size_t)MSLOTS * 4);
  int* smalls = (int*)alloc(256 * 4);
  const size_t fixed = off;

  // Overlay region (reused 3 ways):
  //  phase A: [hsb][Wkb][qf]          (dead after stage 1)
  //  loop:    [P chunk][slabs/retrf]
  //  stage 4: [Wob]
  // Ladder: prefer bf16 partial-slab split-K (plain stores, no RMW), then atomic.
  int chunk = 128, ksplit = 4, modePB = 0;
  {
    const int cc[8] = {4096, 2048, 4096, 2048, 1024, 1024, 512, 128};
    const int kk[8] = {4, 8, 4, 8, 8, 8, 16, 4};
    const int pb[8] = {1, 1, 0, 0, 1, 0, 0, 0};
    const size_t phaseA = (size_t)NROWS * HDIM * 2 + (size_t)HDIM * HDIM * 2 +
                          (size_t)NROWS * HDIM * 4 + 1024;
    for (int ci = 0; ci < 8; ++ci) {
      size_t outBytes = pb[ci] ? (size_t)cc[ci] * HDIM * 2 * kk[ci]
                               : (size_t)cc[ci] * HDIM * 4;
      size_t region = (size_t)cc[ci] * MSLOTS * 2 + outBytes;
      if (region < phaseA) region = phaseA;
      if (fixed + region <= ws_size) {
        chunk = cc[ci]; ksplit = kk[ci]; modePB = pb[ci];
        break;
      }
    }
  }
  bf16_t* hsb = (bf16_t*)(ws + fixed);
  bf16_t* Wkb = (bf16_t*)(ws + fixed + (size_t)NROWS * HDIM * 2);
  float* qf = (float*)(ws + fixed + (size_t)NROWS * HDIM * 2 + (size_t)HDIM * HDIM * 2);
  bf16_t* P = (bf16_t*)(ws + fixed);
  char* after = ws + fixed + (size_t)chunk * MSLOTS * 2;
  bf16_t* retrh = (bf16_t*)after;  // bf16 slabs (modePB)
  float* retrf = (float*)after;    // fp32 accumulator (atomic mode)
  bf16_t* Wob = (bf16_t*)(ws + fixed);  // stage-4 overlay
  const size_t partStride = (size_t)chunk * HDIM;

  // ---- stage 0: compaction + dtype prep ----
  compact_scan<<<1, 1024, 0, stream>>>(usage, posmap, cmask, smalls);
  cvt_f32_bf16<<<(NROWS * HDIM / 8 + 255) / 256, 256, 0, stream>>>(hs, hsb, NROWS * HDIM / 8);
  cvt_f32_bf16<<<(HDIM * HDIM / 8 + 255) / 256, 256, 0, stream>>>(Wk, Wkb, HDIM * HDIM / 8);
  normalize_gather<<<MSLOTS, 256, 0, stream>>>(mk, posmap, smalls, cmkn);
  transpose_gather<<<dim3(HDIM / 32, MSLOTS / 32), 256, 0, stream>>>(mv, posmap, smalls, cVt);

  // ---- stage 1: q = hs @ Wk^T + bk (fp32), then normalize -> qn bf16 ----
  gemm_bt<0><<<dim3(HDIM / 128, NROWS / 128), 256, 0, stream>>>(
      hsb, Wkb, HDIM, HDIM, HDIM, bk, nullptr, nullptr, qf, nullptr, smalls, 1, 0);
  normalize_rows<<<NROWS, 256, 0, stream>>>(qf, qnb);

  // ---- stage 2/3: P = exp(10 * qn@cmkn^T) masked (+row sums); retr = P@V / den ----
  for (int c = 0; c < NROWS; c += chunk) {
    zero_f32<<<(chunk / 4 + 255) / 256, 256, 0, stream>>>(den, chunk / 4);
    gemm_bt<1><<<dim3(MSLOTS / 128, chunk / 128), 256, 0, stream>>>(
        qnb + (size_t)c * HDIM, cmkn, HDIM, HDIM, MSLOTS, nullptr, cmask, den, nullptr, P,
        smalls, 1, 0);
    if (modePB) {
      gemm_bt<4><<<dim3(HDIM / 128, chunk / 128, ksplit), 256, 0, stream>>>(
          P, cVt, MSLOTS, 0, HDIM, nullptr, nullptr, nullptr, nullptr, retrh, smalls, ksplit,
          partStride);
      reduce_scale_b<<<(chunk * HDIM / 8 + 255) / 256, 256, 0, stream>>>(
          retrh, partStride, ksplit, den, retrb + (size_t)c * HDIM, chunk * HDIM / 8);
    } else {
      zero_f32<<<(chunk * HDIM / 4 + 255) / 256, 256, 0, stream>>>(retrf, chunk * HDIM / 4);
      gemm_bt<3><<<dim3(HDIM / 128, chunk / 128, ksplit), 256, 0, stream>>>(
          P, cVt, MSLOTS, 0, HDIM, nullptr, nullptr, nullptr, retrf, nullptr, smalls, ksplit,
          0);
      scale_cvt<<<(chunk * HDIM / 4 + 255) / 256, 256, 0, stream>>>(
          retrf, den, retrb + (size_t)c * HDIM, chunk * HDIM / 4);
    }
  }

  // ---- stage 4: out = retrieved @ Wo^T + bo (fp32) ----
  cvt_f32_bf16<<<(HDIM * HDIM / 8 + 255) / 256, 256, 0, stream>>>(Wo, Wob, HDIM * HDIM / 8);
  gemm_bt<0><<<dim3(HDIM / 128, NROWS / 128), 256, 0, stream>>>(
      retrb, Wob, HDIM, HDIM, HDIM, bo, nullptr, nullptr, out, nullptr, smalls, 1, 0);
}